// Round 9
// baseline (28.252 us; speedup 1.0000x reference)
//
#include <hip/hip_runtime.h>

typedef __attribute__((ext_vector_type(4))) float f32x4;
typedef __attribute__((ext_vector_type(8))) _Float16 f16x8;
typedef __attribute__((ext_vector_type(4))) _Float16 f16x4;

#define D_ 64
#define K_ 512

// 2-limb f16: a = hi + lo (22 mantissa bits), limbs K-concatenated (128 k's).
// Frag layout (identical builder for A and B => within-K-block permutation cancels):
//   halves off = tile*2048 + kb*512 + ko*128 + r*8 + s, k = kb*32+ko*4+(s>>2)*16+(s&3)
// Query limbs NEGATED at staging; acc seeded with 0.5||e||^2 via MFMA C-operand:
//   score = 0.5||e||^2 - c.e  (lo.lo product dropped, ~1.5e-5 error).
// Q=128/block, grid 512 -> 2 blocks/CU (16 waves/CU) for latency hiding.
__global__ __launch_bounds__(512, 4)
void vq_fused(const float* __restrict__ codes,
              const float* __restrict__ codebook,
              float* __restrict__ out) {
  __shared__ _Float16 Af[2][64 * 128];   // 32 KB double-buffered query frags
  __shared__ float esq_s[K_];            // 2 KB
  __shared__ float smin[8][128];         // 4 KB
  __shared__ int   simin[8][128];        // 4 KB
  __shared__ int   best[128];            // 0.5 KB

  const int t = threadIdx.x;
  const int w = t >> 6, l = t & 63, lh = l >> 4, ll = l & 15;
  const long long qb = (long long)blockIdx.x * 128;

  // ---- chunk-0 A loads issued first (HBM latency hides under ef build) ----
  const int aq = t >> 3, dpart = t & 7, d0 = dpart * 8;
  const float* asrc = codes + (qb + aq) * D_ + d0;
  f32x4 av0 = *(const f32x4*)asrc;
  f32x4 av1 = *(const f32x4*)(asrc + 4);

  // ---- build ef frags + ||e||^2 in-register (once per block) ----
  // lane covers entry e = tile*16+ll, dims lh*4 + 16j + {0..3}, j=0..3
  f16x8 ef[4][4];
#pragma unroll
  for (int i = 0; i < 4; ++i) {
    const int e = (w * 4 + i) * 16 + ll;
    const float* src = codebook + e * D_ + lh * 4;
    _Float16 hi[4][4], lo[4][4];
    float es = 0.f;
#pragma unroll
    for (int j = 0; j < 4; ++j) {
      f32x4 v = *(const f32x4*)(src + 16 * j);
#pragma unroll
      for (int si = 0; si < 4; ++si) {
        float a = v[si];
        es += a * a;
        _Float16 h = (_Float16)a;
        hi[j][si] = h;
        lo[j][si] = (_Float16)(a - (float)h);
      }
    }
    es += __shfl_xor(es, 16, 64);         // sum the 4 lh groups
    es += __shfl_xor(es, 32, 64);
    if (lh == 0) esq_s[e] = 0.5f * es;    // read back (transposed) after the barrier
#pragma unroll
    for (int s = 0; s < 8; ++s) {
      ef[i][0][s] = hi[s >> 2][s & 3];          // k = d
      ef[i][1][s] = hi[2 + (s >> 2)][s & 3];    // k = 32 + d'
      ef[i][2][s] = lo[s >> 2][s & 3];          // k = 64 + d
      ef[i][3][s] = lo[2 + (s >> 2)][s & 3];    // k = 96 + d'
    }
  }

  // ---- A staging: thread -> query aq, dims d0..d0+7 (negated limbs) ----
  const int bufStride = 64 * 128;
  _Float16* adstq = &Af[0][(aq >> 4) * 2048 + (aq & 15) * 8];

  auto stage_write = [&](int buf, f32x4 v0, f32x4 v1) {
#pragma unroll
    for (int p = 0; p < 2; ++p) {
      const int d = d0 + 4 * p;
      const int kb = d >> 5, ko = (d >> 2) & 3, j16 = (d >> 4) & 1;
      f16x4 wh, wl;
      f32x4 vv = p ? v1 : v0;
#pragma unroll
      for (int si = 0; si < 4; ++si) {
        float na = -vv[si];                       // negate query
        _Float16 h = (_Float16)na;
        wh[si] = h;
        wl[si] = (_Float16)(na - (float)h);
      }
      _Float16* ad = adstq + buf * bufStride + ko * 128 + j16 * 4;
      *(f16x4*)(ad + kb * 512) = wh;              // hi: k = d
      *(f16x4*)(ad + (2 + kb) * 512) = wl;        // lo: k = 64+d
    }
  };

  stage_write(0, av0, av1);
  __syncthreads();

  // per-lane 0.5||e||^2 for C/D rows: entries (w*4+i)*16 + lh*4 + r
  f32x4 esqr[4];
#pragma unroll
  for (int i = 0; i < 4; ++i)
    esqr[i] = *(const f32x4*)(esq_s + (w * 4 + i) * 16 + lh * 4);

  int cur = 0;
  for (int c = 0; c < 2; ++c) {
    f32x4 nv0, nv1;
    if (c < 1) {                                  // issue-early next chunk
      const float* src = codes + (qb + 64 + aq) * D_ + d0;
      nv0 = *(const f32x4*)src;
      nv1 = *(const f32x4*)(src + 4);
    }

    float mv[4]; int mi[4];
#pragma unroll
    for (int qt = 0; qt < 4; ++qt) {
      f16x8 qf[4];
#pragma unroll
      for (int kb = 0; kb < 4; ++kb)
        qf[kb] = *(const f16x8*)(&Af[0][cur * bufStride + qt * 2048 + kb * 512 + l * 8]);
      mv[qt] = 3.4e38f; mi[qt] = 0;
#pragma unroll
      for (int i = 0; i < 4; ++i) {
        f32x4 a = esqr[i];                        // C-operand seed: 0.5||e||^2
        a = __builtin_amdgcn_mfma_f32_16x16x32_f16(ef[i][0], qf[0], a, 0, 0, 0); // eh.(-ch)
        a = __builtin_amdgcn_mfma_f32_16x16x32_f16(ef[i][1], qf[1], a, 0, 0, 0);
        a = __builtin_amdgcn_mfma_f32_16x16x32_f16(ef[i][2], qf[0], a, 0, 0, 0); // el.(-ch)
        a = __builtin_amdgcn_mfma_f32_16x16x32_f16(ef[i][3], qf[1], a, 0, 0, 0);
        a = __builtin_amdgcn_mfma_f32_16x16x32_f16(ef[i][0], qf[2], a, 0, 0, 0); // eh.(-cl)
        a = __builtin_amdgcn_mfma_f32_16x16x32_f16(ef[i][1], qf[3], a, 0, 0, 0);
#pragma unroll
        for (int r = 0; r < 4; ++r) {
          const int e = (w * 4 + i) * 16 + lh * 4 + r;  // ascending: first-min wins
          if (a[r] < mv[qt]) { mv[qt] = a[r]; mi[qt] = e; }
        }
      }
      // reduce over the 4 lh groups (same query col, different entries)
#pragma unroll
      for (int off = 16; off <= 32; off <<= 1) {
        float ov = __shfl_xor(mv[qt], off, 64);
        int oi = __shfl_xor(mi[qt], off, 64);
        if (ov < mv[qt] || (ov == mv[qt] && oi < mi[qt])) { mv[qt] = ov; mi[qt] = oi; }
      }
    }
    if (l < 16) {
#pragma unroll
      for (int qt = 0; qt < 4; ++qt) {
        smin[w][c * 64 + qt * 16 + ll] = mv[qt];
        simin[w][c * 64 + qt * 16 + ll] = mi[qt];
      }
    }

    if (c < 1) stage_write(cur ^ 1, nv0, nv1);    // write-late, other buffer
    __syncthreads();
    cur ^= 1;
  }

  // ---- combine 8 waves (disjoint ascending entry ranges; tie -> lower index) ----
  if (t < 128) {
    float bv = smin[0][t]; int bi = simin[0][t];
#pragma unroll
    for (int ww = 1; ww < 8; ++ww) {
      float v = smin[ww][t]; int ii = simin[ww][t];
      if (v < bv || (v == bv && ii < bi)) { bv = v; bi = ii; }
    }
    best[t] = bi;
  }
  __syncthreads();

  // ---- gather: exact fp32 rows from global codebook (L2-hot) ----
#pragma unroll
  for (int i2 = 0; i2 < 4; ++i2) {
    const int f = t + 512 * i2;                   // 2048 f32x4 per block
    const int q = f >> 4, g = f & 15;
    const int e = best[q];
    f32x4 v = *(const f32x4*)(codebook + e * D_ + g * 4);
    *(f32x4*)(out + (qb + q) * D_ + g * 4) = v;
  }
}

extern "C" void kernel_launch(void* const* d_in, const int* in_sizes, int n_in,
                              void* d_out, int out_size, void* d_ws, size_t ws_size,
                              hipStream_t stream) {
  const float* codes = (const float*)d_in[0];
  const float* codebook = (const float*)d_in[1];
  float* out = (float*)d_out;
  const int Q = in_sizes[0] / D_;        // 65536
  const int grid = Q / 128;              // 512
  vq_fused<<<grid, 512, 0, stream>>>(codes, codebook, out);
}